// Round 1
// baseline (633.061 us; speedup 1.0000x reference)
//
#include <hip/hip_runtime.h>
#include <hip/hip_bf16.h>

typedef __attribute__((ext_vector_type(8))) short short8;
typedef __attribute__((ext_vector_type(4))) float floatx4;

__device__ __forceinline__ unsigned short f2bf(float x) {
    unsigned u = __float_as_uint(x);
    unsigned r = u + 0x7fffu + ((u >> 16) & 1u);   // RNE
    return (unsigned short)(r >> 16);
}

// ---------------- prep: f32 -> bf16 casts + Wrbf zero-pad to K=32 ----------------
__global__ void prep_kernel(const float* __restrict__ s,
                            const float* __restrict__ Ws1,
                            const float* __restrict__ Ws2,
                            const float* __restrict__ Wrbf,
                            unsigned short* __restrict__ s_bf,
                            unsigned short* __restrict__ ws1_bf,
                            unsigned short* __restrict__ ws2_bf,
                            unsigned short* __restrict__ wrbf_bf,
                            int n_s, int n_w1, int n_w2, int n_wrbf_out, int RB)
{
    int i = blockIdx.x * blockDim.x + threadIdx.x;
    int stride = gridDim.x * blockDim.x;
    int total = n_s + n_w1 + n_w2 + n_wrbf_out;
    for (; i < total; i += stride) {
        if (i < n_s) {
            s_bf[i] = f2bf(s[i]);
        } else if (i < n_s + n_w1) {
            int j = i - n_s;
            ws1_bf[j] = f2bf(Ws1[j]);
        } else if (i < n_s + n_w1 + n_w2) {
            int j = i - n_s - n_w1;
            ws2_bf[j] = f2bf(Ws2[j]);
        } else {
            int j = i - n_s - n_w1 - n_w2;
            int n = j >> 5, k = j & 31;
            wrbf_bf[j] = (k < RB) ? f2bf(Wrbf[n * RB + k]) : (unsigned short)0;
        }
    }
}

// ---------------- main fused edge kernel ----------------
// 1 wave = 16 edges end-to-end. 4 waves / workgroup (256 threads).
#define LN  136   // padded row stride in shorts for S,H tiles (272 B)
#define RLN 40    // padded row stride in shorts for rbf tile (80 B)

__global__ __launch_bounds__(256, 2)
void edge_kernel(const unsigned short* __restrict__ s_bf,
                 const float* __restrict__ vec,          // [Nn,3,128]
                 const float* __restrict__ edge_vec,     // [E,3]
                 const float* __restrict__ edge_dist,    // [E]
                 const float* __restrict__ edge_rbf,     // [E,RB]
                 const unsigned short* __restrict__ ws1_bf, // [128,128]
                 const float* __restrict__ bs1,          // [128]
                 const unsigned short* __restrict__ ws2_bf, // [384,128]
                 const float* __restrict__ bs2,          // [384]
                 const unsigned short* __restrict__ wrbf_bf, // [384,32]
                 const float* __restrict__ brbf,         // [384]
                 const int* __restrict__ eidx,           // [2,E]: row0=dst, row1=src
                 const void* __restrict__ cutoff_raw,
                 float* __restrict__ out_ds,             // [Nn,128]
                 float* __restrict__ out_dvec,           // [Nn,3,128]
                 int E, int RB)
{
    const int tid  = threadIdx.x;
    const int w    = tid >> 6;
    const int lane = tid & 63;
    const int l15  = lane & 15;
    const int q    = lane >> 4;
    const int e0   = (blockIdx.x * 4 + w) * 16;

    // robust cutoff scalar decode (int32 / f32 / int64 / f64)
    float rc;
    {
        float fv = ((const float*)cutoff_raw)[0];
        int   iv = ((const int*)cutoff_raw)[0];
        if (fv > 0.099f && fv < 1.0e6f) rc = fv;
        else if (iv > 0 && iv < 1000000) rc = (float)iv;
        else {
            double dv = ((const double*)cutoff_raw)[0];
            if (dv > 0.099 && dv < 1.0e6) rc = (float)dv;
            else rc = (float)(((const long long*)cutoff_raw)[0]);
        }
    }

    __shared__ unsigned short S_bf[4][16][LN];
    __shared__ unsigned short H_bf[4][16][LN];
    __shared__ unsigned short R_bf[4][16][RLN];
    __shared__ int   m_src[4][16];
    __shared__ int   m_dst[4][16];
    __shared__ float m_fc [4][16];
    __shared__ float m_vn [4][16][3];

    // ---- per-edge meta (lanes 0..15 of each wave) ----
    if (lane < 16) {
        int e = e0 + lane;
        int valid = (e < E);
        int ec = valid ? e : 0;
        int isrc = eidx[E + ec];
        int idst = eidx[ec];
        float d = edge_dist[ec];
        float fc = 0.0f;
        if (valid && d < rc)
            fc = 0.5f * (cosf(3.14159265358979323846f * d / rc) + 1.0f);
        float inv = 1.0f / d;
        m_src[w][lane] = isrc;
        m_dst[w][lane] = idst;
        m_fc [w][lane] = fc;
        m_vn [w][lane][0] = edge_vec[ec * 3 + 0] * inv;
        m_vn [w][lane][1] = edge_vec[ec * 3 + 1] * inv;
        m_vn [w][lane][2] = edge_vec[ec * 3 + 2] * inv;
    }

    // ---- stage rbf tile [16][32] as bf16 (zero-padded K) ----
    for (int idx = lane; idx < 512; idx += 64) {
        int r = idx >> 5, c = idx & 31;
        int e = e0 + r;
        float v = (c < RB && e < E) ? edge_rbf[e * RB + c] : 0.0f;
        R_bf[w][r][c] = f2bf(v);
    }
    __syncthreads();

    // ---- gather-stage S rows (bf16) ----
    #pragma unroll
    for (int it = 0; it < 4; ++it) {
        int r = it * 4 + q;
        int src = m_src[w][r];
        short8 v = ((const short8*)(s_bf + (size_t)src * 128))[l15];
        *((short8*)&S_bf[w][r][l15 * 8]) = v;
    }
    __syncthreads();

    // ---- GEMM1: h = silu(S @ Ws1^T + bs1), M=16 N=128 K=128 ----
    floatx4 acc1[8];
    #pragma unroll
    for (int nj = 0; nj < 8; ++nj) acc1[nj] = (floatx4){0.f, 0.f, 0.f, 0.f};

    #pragma unroll
    for (int ks = 0; ks < 4; ++ks) {
        short8 a = *((const short8*)&S_bf[w][l15][ks * 32 + q * 8]);
        #pragma unroll
        for (int nj = 0; nj < 8; ++nj) {
            short8 b = *((const short8*)(ws1_bf + ((nj * 16 + l15) * 128 + ks * 32 + q * 8)));
            acc1[nj] = __builtin_amdgcn_mfma_f32_16x16x32_bf16(a, b, acc1[nj], 0, 0, 0);
        }
    }
    #pragma unroll
    for (int nj = 0; nj < 8; ++nj) {
        float b1 = bs1[nj * 16 + l15];
        #pragma unroll
        for (int r = 0; r < 4; ++r) {
            float x = acc1[nj][r] + b1;
            float h = x / (1.0f + __expf(-x));
            H_bf[w][q * 4 + r][nj * 16 + l15] = f2bf(h);
        }
    }
    __syncthreads();

    // ---- per-lane edge meta registers (4 rows each) ----
    int dstR[4], srcR[4];
    float fcR[4], vnR[4][3];
    #pragma unroll
    for (int r = 0; r < 4; ++r) {
        int row = q * 4 + r;
        dstR[r] = m_dst[w][row];
        srcR[r] = m_src[w][row];
        fcR[r]  = m_fc [w][row];
        vnR[r][0] = m_vn[w][row][0];
        vnR[r][1] = m_vn[w][row][1];
        vnR[r][2] = m_vn[w][row][2];
    }

    // ---- GEMM2 + rbf MFMA + epilogue, in 3 groups of N=128 ----
    float mvv[8][4];   // msg_vv kept across groups 1 -> 2

    #pragma unroll
    for (int g = 0; g < 3; ++g) {
        floatx4 accP[8], accW[8];
        #pragma unroll
        for (int j = 0; j < 8; ++j) {
            accP[j] = (floatx4){0.f, 0.f, 0.f, 0.f};
            accW[j] = (floatx4){0.f, 0.f, 0.f, 0.f};
        }
        // phi_g = h @ Ws2_g^T
        #pragma unroll
        for (int ks = 0; ks < 4; ++ks) {
            short8 a = *((const short8*)&H_bf[w][l15][ks * 32 + q * 8]);
            #pragma unroll
            for (int j = 0; j < 8; ++j) {
                int n = g * 128 + j * 16 + l15;
                short8 b = *((const short8*)(ws2_bf + ((size_t)n * 128 + ks * 32 + q * 8)));
                accP[j] = __builtin_amdgcn_mfma_f32_16x16x32_bf16(a, b, accP[j], 0, 0, 0);
            }
        }
        // rbf_g = rbf @ Wrbf_g^T (K padded to 32)
        {
            short8 ar = *((const short8*)&R_bf[w][l15][q * 8]);
            #pragma unroll
            for (int j = 0; j < 8; ++j) {
                int n = g * 128 + j * 16 + l15;
                short8 br = *((const short8*)(wrbf_bf + ((size_t)n * 32 + q * 8)));
                accW[j] = __builtin_amdgcn_mfma_f32_16x16x32_bf16(ar, br, accW[j], 0, 0, 0);
            }
        }
        // epilogue
        #pragma unroll
        for (int j = 0; j < 8; ++j) {
            int nl = j * 16 + l15;         // 0..127 within group
            int n  = g * 128 + nl;         // 0..383
            float b2  = bs2[n];
            float brf = brbf[n];
            #pragma unroll
            for (int r = 0; r < 4; ++r) {
                float phi = accP[j][r] + b2;
                float Wv  = (accW[j][r] + brf) * fcR[r];
                float msg = phi * Wv;
                if (g == 0) {
                    atomicAdd(&out_ds[(size_t)dstR[r] * 128 + nl], msg);
                } else if (g == 1) {
                    mvv[j][r] = msg;
                } else {
                    const float* vrow = vec + (size_t)srcR[r] * 384;
                    float* orow = out_dvec + (size_t)dstR[r] * 384;
                    #pragma unroll
                    for (int d = 0; d < 3; ++d) {
                        float contrib = mvv[j][r] * vrow[d * 128 + nl] + vnR[r][d] * msg;
                        atomicAdd(&orow[d * 128 + nl], contrib);
                    }
                }
            }
        }
    }
}

extern "C" void kernel_launch(void* const* d_in, const int* in_sizes, int n_in,
                              void* d_out, int out_size, void* d_ws, size_t ws_size,
                              hipStream_t stream) {
    const float* s        = (const float*)d_in[0];
    const float* vec      = (const float*)d_in[1];
    const float* edge_vec = (const float*)d_in[2];
    const float* edge_dst = (const float*)d_in[3];
    const float* edge_rbf = (const float*)d_in[4];
    const float* Ws1      = (const float*)d_in[5];
    const float* bs1      = (const float*)d_in[6];
    const float* Ws2      = (const float*)d_in[7];
    const float* bs2      = (const float*)d_in[8];
    const float* Wrbf     = (const float*)d_in[9];
    const float* brbf     = (const float*)d_in[10];
    const int*   eidx     = (const int*)d_in[11];
    const void*  cutoff   = d_in[12];

    const int F  = 128;
    const int Nn = in_sizes[0] / F;          // 10000
    const int E  = in_sizes[3];              // 200000
    const int RB = in_sizes[4] / E;          // 20
    const int F3 = 3 * F;                    // 384

    // workspace layout (bf16 buffers)
    unsigned short* s_bf    = (unsigned short*)d_ws;                  // Nn*128
    unsigned short* ws1_bf  = s_bf + (size_t)Nn * F;                  // 128*128
    unsigned short* ws2_bf  = ws1_bf + F * F;                         // 384*128
    unsigned short* wrbf_bf = ws2_bf + F3 * F;                        // 384*32

    int n_s = Nn * F, n_w1 = F * F, n_w2 = F3 * F, n_wr = F3 * 32;

    // zero the accumulation outputs (harness poisons with 0xAA)
    hipMemsetAsync(d_out, 0, (size_t)out_size * sizeof(float), stream);

    {
        int total = n_s + n_w1 + n_w2 + n_wr;
        int blocks = (total + 255) / 256;
        prep_kernel<<<blocks, 256, 0, stream>>>(s, Ws1, Ws2, Wrbf,
                                                s_bf, ws1_bf, ws2_bf, wrbf_bf,
                                                n_s, n_w1, n_w2, n_wr, RB);
    }

    float* out_ds   = (float*)d_out;
    float* out_dvec = out_ds + (size_t)Nn * F;

    int blocks = (E + 63) / 64;   // 64 edges per workgroup
    edge_kernel<<<blocks, 256, 0, stream>>>(s_bf, vec, edge_vec, edge_dst, edge_rbf,
                                            ws1_bf, bs1, ws2_bf, bs2, wrbf_bf, brbf,
                                            eidx, cutoff, out_ds, out_dvec, E, RB);
}